// Round 1
// baseline (5229.673 us; speedup 1.0000x reference)
//
#include <hip/hip_runtime.h>

#define NPTS 8192
#define NP   2048
#define NB   8
#define CIN  128
#define COUT 256
#define KNN_K 16

__device__ __forceinline__ float mulrn(float a, float b){ return __fmul_rn(a,b); }
__device__ __forceinline__ float addrn(float a, float b){ return __fadd_rn(a,b); }
__device__ __forceinline__ float subrn(float a, float b){ return __fsub_rn(a,b); }

// ---------------- K1: farthest point sampling (one block per batch) ----------
__global__ __launch_bounds__(1024) void k_fps(const float* __restrict__ xyz,
                                              float* __restrict__ out_xyz) {
  const int b = blockIdx.x;
  const int tid = threadIdx.x;
  const float* base = xyz + (size_t)b * NPTS * 3;
  float px[8], py[8], pz[8], dist[8];
  const int i0 = tid * 8;
#pragma unroll
  for (int j = 0; j < 8; ++j) {
    px[j] = base[(i0 + j) * 3 + 0];
    py[j] = base[(i0 + j) * 3 + 1];
    pz[j] = base[(i0 + j) * 3 + 2];
    dist[j] = 1e10f;
  }
  __shared__ float s_cx, s_cy, s_cz;
  __shared__ float s_pval[16];
  __shared__ int   s_pidx[16];
  __shared__ int   s_res;
  if (tid == 0) {
    size_t o = (size_t)b * NP * 3;
    out_xyz[o + 0] = px[0]; out_xyz[o + 1] = py[0]; out_xyz[o + 2] = pz[0];
    s_cx = px[0]; s_cy = py[0]; s_cz = pz[0];
  }
  __syncthreads();
#pragma unroll 1
  for (int s = 1; s < NP; ++s) {
    const float cx = s_cx, cy = s_cy, cz = s_cz;
    float bv = -1.0f; int bi = 0;
#pragma unroll
    for (int j = 0; j < 8; ++j) {
      float dx = subrn(px[j], cx);
      float dy = subrn(py[j], cy);
      float dz = subrn(pz[j], cz);
      float dd = addrn(addrn(mulrn(dx, dx), mulrn(dy, dy)), mulrn(dz, dz));
      float dm = fminf(dist[j], dd);
      dist[j] = dm;
      bool g = dm > bv;           // strict > keeps lowest index among ties
      bi = g ? (i0 + j) : bi;
      bv = g ? dm : bv;
    }
#pragma unroll
    for (int off = 1; off < 64; off <<= 1) {
      float ov = __shfl_xor(bv, off, 64);
      int   oi = __shfl_xor(bi, off, 64);
      bool take = (ov > bv) || ((ov == bv) && (oi < bi));
      bv = take ? ov : bv;
      bi = take ? oi : bi;
    }
    if ((tid & 63) == 0) { s_pval[tid >> 6] = bv; s_pidx[tid >> 6] = bi; }
    __syncthreads();
    if (tid < 16) {
      float v = s_pval[tid]; int ix = s_pidx[tid];
#pragma unroll
      for (int off = 1; off < 16; off <<= 1) {
        float ov = __shfl_xor(v, off, 16);
        int   oi = __shfl_xor(ix, off, 16);
        bool take = (ov > v) || ((ov == v) && (oi < ix));
        v = take ? ov : v;
        ix = take ? oi : ix;
      }
      if (tid == 0) s_res = ix;
    }
    __syncthreads();
    const int ri = s_res;
    if ((ri >> 3) == tid) {
      const int j = ri & 7;
      size_t o = ((size_t)b * NP + s) * 3;
      out_xyz[o + 0] = px[j]; out_xyz[o + 1] = py[j]; out_xyz[o + 2] = pz[j];
      s_cx = px[j]; s_cy = py[j]; s_cz = pz[j];
    }
    __syncthreads();
  }
}

// ---------------- K2: 16-NN per sampled point (one wave per query) -----------
__global__ __launch_bounds__(256) void k_knn(const float* __restrict__ xyz,
                                             const float* __restrict__ new_xyz,
                                             int* __restrict__ knn) {
  __shared__ float4 s_pts[NPTS];   // 128 KB
  const int gq0 = blockIdx.x * 64;
  const int b = gq0 >> 11;
  const float* base = xyz + (size_t)b * NPTS * 3;
  for (int i = threadIdx.x; i < NPTS; i += 256) {
    float x = base[i * 3 + 0], y = base[i * 3 + 1], z = base[i * 3 + 2];
    float n = addrn(addrn(mulrn(x, x), mulrn(y, y)), mulrn(z, z));
    s_pts[i] = make_float4(x, y, z, n);
  }
  __syncthreads();
  const int wave = threadIdx.x >> 6;
  const int lane = threadIdx.x & 63;
#pragma unroll 1
  for (int qi = 0; qi < 16; ++qi) {
    const int gq = gq0 + wave * 16 + qi;
    const float qx = new_xyz[(size_t)gq * 3 + 0];
    const float qy = new_xyz[(size_t)gq * 3 + 1];
    const float qz = new_xyz[(size_t)gq * 3 + 2];
    const float qn = addrn(addrn(mulrn(qx, qx), mulrn(qy, qy)), mulrn(qz, qz));
    // top-16 (sorted descending = worst-first) lives in lanes 0..15
    float bd = (lane < 16) ? 1e30f : -1e30f;
    int   bi = 0;
    float r = 1e30f;   // current worst of the 16 (uniform)
#pragma unroll 1
    for (int c0 = 0; c0 < NPTS; c0 += 64) {
      float4 p = s_pts[c0 + lane];
      float dot = addrn(addrn(mulrn(qx, p.x), mulrn(qy, p.y)), mulrn(qz, p.z));
      float dd = addrn(addrn(mulrn(-2.0f, dot), qn), p.w);
      unsigned long long m = __ballot(dd < r);
      while (m) {
        int src = __builtin_ctzll(m);
        m &= (m - 1);
        float v = __shfl(dd, src, 64);
        if (v < r) {                       // uniform re-check (r may have moved)
          int vi = c0 + src;
          float bdn = __shfl_down(bd, 1, 64);
          int   bin_ = __shfl_down(bi, 1, 64);
          bool c1 = bdn > v;
          bool c2 = bd > v;
          float nb  = c1 ? bdn  : (c2 ? v  : bd);
          int   nbi = c1 ? bin_ : (c2 ? vi : bi);
          bd = (lane < 16) ? nb  : -1e30f;
          bi = (lane < 16) ? nbi : bi;
          r = __shfl(bd, 0, 64);
        }
      }
    }
    if (lane < 16) knn[(size_t)gq * KNN_K + lane] = bi;
  }
}

// -------- K3/K5: grouped linear (gather + GEMM); mode 0 = stats, 1 = final ---
__global__ __launch_bounds__(256) void k_gemm(const float* __restrict__ feat,
    const float* __restrict__ xyz, const float* __restrict__ new_xyz,
    const int* __restrict__ knn, const float* __restrict__ W,
    float* __restrict__ part_sum, float* __restrict__ part_sq,
    const float* __restrict__ scale, const float* __restrict__ bias,
    float* __restrict__ out, int mode) {
  __shared__ float sg[16][132];   // one query's 16 rows; c0..127 feat, 128..130 relxyz, 131 pad
  const int d = threadIdx.x;
  float w[132];
#pragma unroll
  for (int c = 0; c < 132; ++c) {
    if (c < 128)      w[c] = W[(size_t)(3 + c) * COUT + d];     // feature rows
    else if (c < 131) w[c] = W[(size_t)(c - 128) * COUT + d];   // xyz rows 0..2
    else              w[c] = 0.0f;
  }
  float psum = 0.0f, psq = 0.0f;
  float sc = 0.0f, bb = 0.0f;
  if (mode == 1) { sc = scale[d]; bb = bias[d]; }
#pragma unroll 1
  for (int i = 0; i < 64; ++i) {
    const int gq = blockIdx.x * 64 + i;
    const int b = gq >> 11;
    {
      const int row = d >> 4, sub = d & 15;
      const int nidx = knn[(size_t)gq * KNN_K + row];
      const float* frow = feat + ((size_t)b * NPTS + nidx) * CIN;
      const float4 a0 = *(const float4*)(frow + sub * 8);
      const float4 a1 = *(const float4*)(frow + sub * 8 + 4);
      *(float4*)&sg[row][sub * 8]     = a0;
      *(float4*)&sg[row][sub * 8 + 4] = a1;
      if (sub == 0) {
        const float gx = xyz[((size_t)b * NPTS + nidx) * 3 + 0];
        const float gy = xyz[((size_t)b * NPTS + nidx) * 3 + 1];
        const float gz = xyz[((size_t)b * NPTS + nidx) * 3 + 2];
        const float qx = new_xyz[(size_t)gq * 3 + 0];
        const float qy = new_xyz[(size_t)gq * 3 + 1];
        const float qz = new_xyz[(size_t)gq * 3 + 2];
        *(float4*)&sg[row][128] = make_float4(gx - qx, gy - qy, gz - qz, 0.0f);
      }
    }
    __syncthreads();
    float hmax = -1e30f, hmin = 1e30f;
#pragma unroll 1
    for (int k = 0; k < 16; ++k) {
      float a0 = 0.f, a1 = 0.f, a2 = 0.f, a3 = 0.f;
#pragma unroll
      for (int c4 = 0; c4 < 33; ++c4) {
        float4 g = *(const float4*)&sg[k][c4 * 4];
        a0 = fmaf(g.x, w[c4 * 4 + 0], a0);
        a1 = fmaf(g.y, w[c4 * 4 + 1], a1);
        a2 = fmaf(g.z, w[c4 * 4 + 2], a2);
        a3 = fmaf(g.w, w[c4 * 4 + 3], a3);
      }
      float h = (a0 + a1) + (a2 + a3);
      if (mode == 0) { psum += h; psq = fmaf(h, h, psq); }
      else           { hmax = fmaxf(hmax, h); hmin = fminf(hmin, h); }
    }
    if (mode == 1) {
      float hsel = (sc >= 0.0f) ? hmax : hmin;   // BN affine is monotone per sign
      float o = fmaxf(fmaf(sc, hsel, bb), 0.0f);
      out[(size_t)gq * COUT + d] = o;
    }
    __syncthreads();
  }
  if (mode == 0) {
    part_sum[(size_t)blockIdx.x * COUT + d] = psum;
    part_sq [(size_t)blockIdx.x * COUT + d] = psq;
  }
}

// ---------------- K4: fold partials into BN scale/bias -----------------------
__global__ __launch_bounds__(256) void k_stats(const float* __restrict__ part_sum,
    const float* __restrict__ part_sq, const float* __restrict__ gamma,
    const float* __restrict__ beta, float* __restrict__ scale,
    float* __restrict__ bias) {
  const int d = threadIdx.x;
  float s = 0.0f, q = 0.0f;
  for (int bl = 0; bl < 256; ++bl) {
    s += part_sum[(size_t)bl * COUT + d];
    q += part_sq[(size_t)bl * COUT + d];
  }
  const float inv = 1.0f / 262144.0f;
  float mean = s * inv;
  float var = q * inv - mean * mean;
  float scv = gamma[d] / sqrtf(var + 1e-5f);
  scale[d] = scv;
  bias[d] = beta[d] - mean * scv;
}

extern "C" void kernel_launch(void* const* d_in, const int* in_sizes, int n_in,
                              void* d_out, int out_size, void* d_ws, size_t ws_size,
                              hipStream_t stream) {
  const float* xyz   = (const float*)d_in[0];
  const float* feat  = (const float*)d_in[1];
  const float* W     = (const float*)d_in[2];
  const float* gamma = (const float*)d_in[3];
  const float* beta  = (const float*)d_in[4];
  float* out_xyz = (float*)d_out;
  float* out_nf  = out_xyz + (size_t)NB * NP * 3;   // 49152 floats of new_xyz first

  int*   knn      = (int*)d_ws;                                  // 16384*16 int
  float* part_sum = (float*)((char*)d_ws + (1 << 20));           // 256*256
  float* part_sq  = part_sum + 256 * COUT;                       // 256*256
  float* scale    = part_sq + 256 * COUT;                        // 256
  float* bias     = scale + COUT;                                // 256

  hipLaunchKernelGGL(k_fps, dim3(NB), dim3(1024), 0, stream, xyz, out_xyz);
  hipLaunchKernelGGL(k_knn, dim3(256), dim3(256), 0, stream, xyz, out_xyz, knn);
  hipLaunchKernelGGL(k_gemm, dim3(256), dim3(256), 0, stream, feat, xyz, out_xyz,
                     knn, W, part_sum, part_sq, (const float*)nullptr,
                     (const float*)nullptr, (float*)nullptr, 0);
  hipLaunchKernelGGL(k_stats, dim3(1), dim3(256), 0, stream, part_sum, part_sq,
                     gamma, beta, scale, bias);
  hipLaunchKernelGGL(k_gemm, dim3(256), dim3(256), 0, stream, feat, xyz, out_xyz,
                     knn, W, (float*)nullptr, (float*)nullptr, scale, bias,
                     out_nf, 1);
}

// Round 2
// 4406.573 us; speedup vs baseline: 1.1868x; 1.1868x over previous
//
#include <hip/hip_runtime.h>

#define NPTS 8192
#define NP   2048
#define NB   8
#define CIN  128
#define COUT 256
#define KNN_K 16

__device__ __forceinline__ float mulrn(float a, float b){ return __fmul_rn(a,b); }
__device__ __forceinline__ float addrn(float a, float b){ return __fadd_rn(a,b); }
__device__ __forceinline__ float subrn(float a, float b){ return __fsub_rn(a,b); }

// ---------------- K1: farthest point sampling (one block per batch) ----------
// 1024 threads; 8 points/thread in registers; LDS mirror of points for
// centroid broadcast. Per step: value-only max reduce + equality rescan for
// the index (atomicMin => lowest index on ties, matching np.argmax).
__global__ __launch_bounds__(1024) void k_fps(const float* __restrict__ xyz,
                                              float* __restrict__ out_xyz) {
  const int b = blockIdx.x;
  const int tid = threadIdx.x;
  const int lane = tid & 63;
  const int wid = tid >> 6;                 // 0..15
  const float* base = xyz + (size_t)b * NPTS * 3;

  __shared__ float s_x[NPTS];               // 32 KB
  __shared__ float s_y[NPTS];               // 32 KB
  __shared__ float s_z[NPTS];               // 32 KB
  __shared__ float s_wmax[2][16];
  __shared__ int   s_widx[2];

  float px[8], py[8], pz[8], dist[8];
  const int i0 = tid * 8;
  {
    const float4* b4 = (const float4*)(base + (size_t)i0 * 3);  // 96B/thread, 16B-aligned
    float4 v0 = b4[0], v1 = b4[1], v2 = b4[2], v3 = b4[3], v4 = b4[4], v5 = b4[5];
    px[0]=v0.x; py[0]=v0.y; pz[0]=v0.z;
    px[1]=v0.w; py[1]=v1.x; pz[1]=v1.y;
    px[2]=v1.z; py[2]=v1.w; pz[2]=v2.x;
    px[3]=v2.y; py[3]=v2.z; pz[3]=v2.w;
    px[4]=v3.x; py[4]=v3.y; pz[4]=v3.z;
    px[5]=v3.w; py[5]=v4.x; pz[5]=v4.y;
    px[6]=v4.z; py[6]=v4.w; pz[6]=v5.x;
    px[7]=v5.y; py[7]=v5.z; pz[7]=v5.w;
  }
#pragma unroll
  for (int j = 0; j < 8; ++j) {
    s_x[i0 + j] = px[j]; s_y[i0 + j] = py[j]; s_z[i0 + j] = pz[j];
    dist[j] = 1e10f;
  }
  if (tid == 0) {
    s_widx[0] = 0x7fffffff; s_widx[1] = 0x7fffffff;
    size_t o = (size_t)b * NP * 3;
    out_xyz[o + 0] = px[0]; out_xyz[o + 1] = py[0]; out_xyz[o + 2] = pz[0];
  }
  __syncthreads();
  float cx = s_x[0], cy = s_y[0], cz = s_z[0];   // first centroid = point 0

#pragma unroll 1
  for (int s = 1; s < NP; ++s) {
    const int p = s & 1;
    float vmax = -1.0f;
#pragma unroll
    for (int j = 0; j < 8; ++j) {
      float dx = subrn(px[j], cx);
      float dy = subrn(py[j], cy);
      float dz = subrn(pz[j], cz);
      float dd = addrn(addrn(mulrn(dx, dx), mulrn(dy, dy)), mulrn(dz, dz));
      float dm = fminf(dist[j], dd);
      dist[j] = dm;
      vmax = fmaxf(vmax, dm);
    }
#pragma unroll
    for (int off = 1; off < 64; off <<= 1)
      vmax = fmaxf(vmax, __shfl_xor(vmax, off, 64));
    if (lane == 0) s_wmax[p][wid] = vmax;
    __syncthreads();                       // barrier 1: wave maxima visible
    const float4 m0 = *(const float4*)&s_wmax[p][0];
    const float4 m1 = *(const float4*)&s_wmax[p][4];
    const float4 m2 = *(const float4*)&s_wmax[p][8];
    const float4 m3 = *(const float4*)&s_wmax[p][12];
    const float M = fmaxf(
        fmaxf(fmaxf(fmaxf(m0.x, m0.y), fmaxf(m0.z, m0.w)),
              fmaxf(fmaxf(m1.x, m1.y), fmaxf(m1.z, m1.w))),
        fmaxf(fmaxf(fmaxf(m2.x, m2.y), fmaxf(m2.z, m2.w)),
              fmaxf(fmaxf(m3.x, m3.y), fmaxf(m3.z, m3.w))));
    int hit = 0x7fffffff;
#pragma unroll
    for (int j = 7; j >= 0; --j) hit = (dist[j] == M) ? (i0 + j) : hit;
    if (hit != 0x7fffffff) atomicMin(&s_widx[p], hit);
    if (tid == 0) s_widx[p ^ 1] = 0x7fffffff;   // reset slot for step s+1 (2 barriers ahead of use)
    __syncthreads();                       // barrier 2: winner index final
    const int ri = s_widx[p];
    cx = s_x[ri]; cy = s_y[ri]; cz = s_z[ri];   // broadcast reads
    if (tid == 0) {
      size_t o = ((size_t)b * NP + s) * 3;
      out_xyz[o + 0] = cx; out_xyz[o + 1] = cy; out_xyz[o + 2] = cz;
    }
  }
}

// ---------------- K2: 16-NN per sampled point (one wave per query) -----------
__global__ __launch_bounds__(256) void k_knn(const float* __restrict__ xyz,
                                             const float* __restrict__ new_xyz,
                                             int* __restrict__ knn) {
  __shared__ float4 s_pts[NPTS];   // 128 KB
  const int gq0 = blockIdx.x * 64;
  const int b = gq0 >> 11;
  const float* base = xyz + (size_t)b * NPTS * 3;
  for (int i = threadIdx.x; i < NPTS; i += 256) {
    float x = base[i * 3 + 0], y = base[i * 3 + 1], z = base[i * 3 + 2];
    float n = addrn(addrn(mulrn(x, x), mulrn(y, y)), mulrn(z, z));
    s_pts[i] = make_float4(x, y, z, n);
  }
  __syncthreads();
  const int wave = threadIdx.x >> 6;
  const int lane = threadIdx.x & 63;
#pragma unroll 1
  for (int qi = 0; qi < 16; ++qi) {
    const int gq = gq0 + wave * 16 + qi;
    const float qx = new_xyz[(size_t)gq * 3 + 0];
    const float qy = new_xyz[(size_t)gq * 3 + 1];
    const float qz = new_xyz[(size_t)gq * 3 + 2];
    const float qn = addrn(addrn(mulrn(qx, qx), mulrn(qy, qy)), mulrn(qz, qz));
    // top-16 (sorted descending = worst-first) lives in lanes 0..15
    float bd = (lane < 16) ? 1e30f : -1e30f;
    int   bi = 0;
    float r = 1e30f;   // current worst of the 16 (uniform)
#pragma unroll 1
    for (int c0 = 0; c0 < NPTS; c0 += 64) {
      float4 p = s_pts[c0 + lane];
      float dot = addrn(addrn(mulrn(qx, p.x), mulrn(qy, p.y)), mulrn(qz, p.z));
      float dd = addrn(addrn(mulrn(-2.0f, dot), qn), p.w);
      unsigned long long m = __ballot(dd < r);
      while (m) {
        int src = __builtin_ctzll(m);
        m &= (m - 1);
        float v = __shfl(dd, src, 64);
        if (v < r) {                       // uniform re-check (r may have moved)
          int vi = c0 + src;
          float bdn = __shfl_down(bd, 1, 64);
          int   bin_ = __shfl_down(bi, 1, 64);
          bool c1 = bdn > v;
          bool c2 = bd > v;
          float nb  = c1 ? bdn  : (c2 ? v  : bd);
          int   nbi = c1 ? bin_ : (c2 ? vi : bi);
          bd = (lane < 16) ? nb  : -1e30f;
          bi = (lane < 16) ? nbi : bi;
          r = __shfl(bd, 0, 64);
        }
      }
    }
    if (lane < 16) knn[(size_t)gq * KNN_K + lane] = bi;
  }
}

// -------- K3/K5: grouped linear (gather + GEMM); mode 0 = stats, 1 = final ---
__global__ __launch_bounds__(256) void k_gemm(const float* __restrict__ feat,
    const float* __restrict__ xyz, const float* __restrict__ new_xyz,
    const int* __restrict__ knn, const float* __restrict__ W,
    float* __restrict__ part_sum, float* __restrict__ part_sq,
    const float* __restrict__ scale, const float* __restrict__ bias,
    float* __restrict__ out, int mode) {
  __shared__ float sg[16][132];   // one query's 16 rows; c0..127 feat, 128..130 relxyz, 131 pad
  const int d = threadIdx.x;
  float w[132];
#pragma unroll
  for (int c = 0; c < 132; ++c) {
    if (c < 128)      w[c] = W[(size_t)(3 + c) * COUT + d];     // feature rows
    else if (c < 131) w[c] = W[(size_t)(c - 128) * COUT + d];   // xyz rows 0..2
    else              w[c] = 0.0f;
  }
  float psum = 0.0f, psq = 0.0f;
  float sc = 0.0f, bb = 0.0f;
  if (mode == 1) { sc = scale[d]; bb = bias[d]; }
#pragma unroll 1
  for (int i = 0; i < 64; ++i) {
    const int gq = blockIdx.x * 64 + i;
    const int b = gq >> 11;
    {
      const int row = d >> 4, sub = d & 15;
      const int nidx = knn[(size_t)gq * KNN_K + row];
      const float* frow = feat + ((size_t)b * NPTS + nidx) * CIN;
      const float4 a0 = *(const float4*)(frow + sub * 8);
      const float4 a1 = *(const float4*)(frow + sub * 8 + 4);
      *(float4*)&sg[row][sub * 8]     = a0;
      *(float4*)&sg[row][sub * 8 + 4] = a1;
      if (sub == 0) {
        const float gx = xyz[((size_t)b * NPTS + nidx) * 3 + 0];
        const float gy = xyz[((size_t)b * NPTS + nidx) * 3 + 1];
        const float gz = xyz[((size_t)b * NPTS + nidx) * 3 + 2];
        const float qx = new_xyz[(size_t)gq * 3 + 0];
        const float qy = new_xyz[(size_t)gq * 3 + 1];
        const float qz = new_xyz[(size_t)gq * 3 + 2];
        *(float4*)&sg[row][128] = make_float4(gx - qx, gy - qy, gz - qz, 0.0f);
      }
    }
    __syncthreads();
    float hmax = -1e30f, hmin = 1e30f;
#pragma unroll 1
    for (int k = 0; k < 16; ++k) {
      float a0 = 0.f, a1 = 0.f, a2 = 0.f, a3 = 0.f;
#pragma unroll
      for (int c4 = 0; c4 < 33; ++c4) {
        float4 g = *(const float4*)&sg[k][c4 * 4];
        a0 = fmaf(g.x, w[c4 * 4 + 0], a0);
        a1 = fmaf(g.y, w[c4 * 4 + 1], a1);
        a2 = fmaf(g.z, w[c4 * 4 + 2], a2);
        a3 = fmaf(g.w, w[c4 * 4 + 3], a3);
      }
      float h = (a0 + a1) + (a2 + a3);
      if (mode == 0) { psum += h; psq = fmaf(h, h, psq); }
      else           { hmax = fmaxf(hmax, h); hmin = fminf(hmin, h); }
    }
    if (mode == 1) {
      float hsel = (sc >= 0.0f) ? hmax : hmin;   // BN affine is monotone per sign
      float o = fmaxf(fmaf(sc, hsel, bb), 0.0f);
      out[(size_t)gq * COUT + d] = o;
    }
    __syncthreads();
  }
  if (mode == 0) {
    part_sum[(size_t)blockIdx.x * COUT + d] = psum;
    part_sq [(size_t)blockIdx.x * COUT + d] = psq;
  }
}

// ---------------- K4: fold partials into BN scale/bias -----------------------
__global__ __launch_bounds__(256) void k_stats(const float* __restrict__ part_sum,
    const float* __restrict__ part_sq, const float* __restrict__ gamma,
    const float* __restrict__ beta, float* __restrict__ scale,
    float* __restrict__ bias) {
  const int d = threadIdx.x;
  float s = 0.0f, q = 0.0f;
  for (int bl = 0; bl < 256; ++bl) {
    s += part_sum[(size_t)bl * COUT + d];
    q += part_sq[(size_t)bl * COUT + d];
  }
  const float inv = 1.0f / 262144.0f;
  float mean = s * inv;
  float var = q * inv - mean * mean;
  float scv = gamma[d] / sqrtf(var + 1e-5f);
  scale[d] = scv;
  bias[d] = beta[d] - mean * scv;
}

extern "C" void kernel_launch(void* const* d_in, const int* in_sizes, int n_in,
                              void* d_out, int out_size, void* d_ws, size_t ws_size,
                              hipStream_t stream) {
  const float* xyz   = (const float*)d_in[0];
  const float* feat  = (const float*)d_in[1];
  const float* W     = (const float*)d_in[2];
  const float* gamma = (const float*)d_in[3];
  const float* beta  = (const float*)d_in[4];
  float* out_xyz = (float*)d_out;
  float* out_nf  = out_xyz + (size_t)NB * NP * 3;   // 49152 floats of new_xyz first

  int*   knn      = (int*)d_ws;                                  // 16384*16 int
  float* part_sum = (float*)((char*)d_ws + (1 << 20));           // 256*256
  float* part_sq  = part_sum + 256 * COUT;                       // 256*256
  float* scale    = part_sq + 256 * COUT;                        // 256
  float* bias     = scale + COUT;                                // 256

  hipLaunchKernelGGL(k_fps, dim3(NB), dim3(1024), 0, stream, xyz, out_xyz);
  hipLaunchKernelGGL(k_knn, dim3(256), dim3(256), 0, stream, xyz, out_xyz, knn);
  hipLaunchKernelGGL(k_gemm, dim3(256), dim3(256), 0, stream, feat, xyz, out_xyz,
                     knn, W, part_sum, part_sq, (const float*)nullptr,
                     (const float*)nullptr, (float*)nullptr, 0);
  hipLaunchKernelGGL(k_stats, dim3(1), dim3(256), 0, stream, part_sum, part_sq,
                     gamma, beta, scale, bias);
  hipLaunchKernelGGL(k_gemm, dim3(256), dim3(256), 0, stream, feat, xyz, out_xyz,
                     knn, W, (float*)nullptr, (float*)nullptr, scale, bias,
                     out_nf, 1);
}

// Round 3
// 3149.391 us; speedup vs baseline: 1.6605x; 1.3992x over previous
//
#include <hip/hip_runtime.h>

#define NPTS 8192
#define NP   2048
#define NB   8
#define CIN  128
#define COUT 256
#define KNN_K 16
#define GQ_TOTAL (NB * NP)          // 16384
#define GEMM_BLOCKS 512
#define GEMM_QPB (GQ_TOTAL / GEMM_BLOCKS)   // 32

__device__ __forceinline__ float mulrn(float a, float b){ return __fmul_rn(a,b); }
__device__ __forceinline__ float addrn(float a, float b){ return __fadd_rn(a,b); }
__device__ __forceinline__ float subrn(float a, float b){ return __fsub_rn(a,b); }

// ---------------- K1: farthest point sampling (one block per batch) ----------
// 512 threads, 16 pts/thread in registers; LDS mirror for centroid broadcast.
// Per step: value+index packed into u64 -> one shfl reduce + ONE barrier.
// Pack: (float_bits(dist) << 32) | (8191 - idx): u64-max => max dist, ties ->
// lowest index (np.argmax semantics). Positive-float bits are monotone.
__global__ __launch_bounds__(512) void k_fps(const float* __restrict__ xyz,
                                             float* __restrict__ out_xyz) {
  const int b = blockIdx.x;
  const int tid = threadIdx.x;
  const int lane = tid & 63;
  const int wid = tid >> 6;                 // 0..7
  const float* base = xyz + (size_t)b * NPTS * 3;

  __shared__ float s_x[NPTS];               // 32 KB
  __shared__ float s_y[NPTS];               // 32 KB
  __shared__ float s_z[NPTS];               // 32 KB
  __shared__ unsigned long long s_red[2][8];

  float px[16], py[16], pz[16], dist[16];
  const int i0 = tid * 16;
  {
    const float4* b4 = (const float4*)(base + (size_t)i0 * 3);  // 192B/thread
#pragma unroll
    for (int q = 0; q < 4; ++q) {
      float4 v0 = b4[q * 3 + 0], v1 = b4[q * 3 + 1], v2 = b4[q * 3 + 2];
      const int j = q * 4;
      px[j+0]=v0.x; py[j+0]=v0.y; pz[j+0]=v0.z;
      px[j+1]=v0.w; py[j+1]=v1.x; pz[j+1]=v1.y;
      px[j+2]=v1.z; py[j+2]=v1.w; pz[j+2]=v2.x;
      px[j+3]=v2.y; py[j+3]=v2.z; pz[j+3]=v2.w;
    }
  }
#pragma unroll
  for (int j = 0; j < 16; ++j) {
    s_x[i0 + j] = px[j]; s_y[i0 + j] = py[j]; s_z[i0 + j] = pz[j];
    dist[j] = 1e10f;
  }
  if (tid == 0) {
    size_t o = (size_t)b * NP * 3;
    out_xyz[o + 0] = px[0]; out_xyz[o + 1] = py[0]; out_xyz[o + 2] = pz[0];
  }
  __syncthreads();
  float cx = s_x[0], cy = s_y[0], cz = s_z[0];

#pragma unroll 1
  for (int s = 1; s < NP; ++s) {
    const int p = s & 1;
    float bv = -1.0f; int bi = 0;
#pragma unroll
    for (int j = 0; j < 16; ++j) {
      float dx = subrn(px[j], cx);
      float dy = subrn(py[j], cy);
      float dz = subrn(pz[j], cz);
      float dd = addrn(addrn(mulrn(dx, dx), mulrn(dy, dy)), mulrn(dz, dz));
      float dm = fminf(dist[j], dd);
      dist[j] = dm;
      bool g = dm > bv;                    // strict: keeps lowest index in-thread
      bi = g ? (i0 + j) : bi;
      bv = g ? dm : bv;
    }
    unsigned long long pk =
        ((unsigned long long)__float_as_uint(bv) << 32) | (unsigned)(8191 - bi);
#pragma unroll
    for (int off = 1; off < 64; off <<= 1) {
      unsigned long long ov = __shfl_xor(pk, off, 64);
      pk = (ov > pk) ? ov : pk;
    }
    if (lane == 0) s_red[p][wid] = pk;
    __syncthreads();                       // the ONE barrier per step
    unsigned long long m = s_red[p][0];
    unsigned long long t1 = s_red[p][1], t2 = s_red[p][2], t3 = s_red[p][3];
    unsigned long long t4 = s_red[p][4], t5 = s_red[p][5], t6 = s_red[p][6];
    unsigned long long t7 = s_red[p][7];
    m = (t1 > m) ? t1 : m;  m = (t2 > m) ? t2 : m;  m = (t3 > m) ? t3 : m;
    m = (t4 > m) ? t4 : m;  m = (t5 > m) ? t5 : m;  m = (t6 > m) ? t6 : m;
    m = (t7 > m) ? t7 : m;
    const int ri = 8191 - (int)((unsigned)(m & 0xffffffffu));
    cx = s_x[ri]; cy = s_y[ri]; cz = s_z[ri];   // broadcast reads
    if (tid == 0) {
      size_t o = ((size_t)b * NP + s) * 3;
      out_xyz[o + 0] = cx; out_xyz[o + 1] = cy; out_xyz[o + 2] = cz;
    }
  }
}

// ---------------- K2: 16-NN per sampled point (one wave per query) -----------
__global__ __launch_bounds__(256) void k_knn(const float* __restrict__ xyz,
                                             const float* __restrict__ new_xyz,
                                             int* __restrict__ knn) {
  __shared__ float4 s_pts[NPTS];   // 128 KB
  const int gq0 = blockIdx.x * 64;
  const int b = gq0 >> 11;
  const float* base = xyz + (size_t)b * NPTS * 3;
  for (int i = threadIdx.x; i < NPTS; i += 256) {
    float x = base[i * 3 + 0], y = base[i * 3 + 1], z = base[i * 3 + 2];
    float n = addrn(addrn(mulrn(x, x), mulrn(y, y)), mulrn(z, z));
    s_pts[i] = make_float4(x, y, z, n);
  }
  __syncthreads();
  const int wave = threadIdx.x >> 6;
  const int lane = threadIdx.x & 63;
#pragma unroll 1
  for (int qi = 0; qi < 16; ++qi) {
    const int gq = gq0 + wave * 16 + qi;
    const float qx = new_xyz[(size_t)gq * 3 + 0];
    const float qy = new_xyz[(size_t)gq * 3 + 1];
    const float qz = new_xyz[(size_t)gq * 3 + 2];
    const float qn = addrn(addrn(mulrn(qx, qx), mulrn(qy, qy)), mulrn(qz, qz));
    float bd = (lane < 16) ? 1e30f : -1e30f;
    int   bi = 0;
    float r = 1e30f;
#pragma unroll 1
    for (int c0 = 0; c0 < NPTS; c0 += 64) {
      float4 p = s_pts[c0 + lane];
      float dot = addrn(addrn(mulrn(qx, p.x), mulrn(qy, p.y)), mulrn(qz, p.z));
      float dd = addrn(addrn(mulrn(-2.0f, dot), qn), p.w);
      unsigned long long m = __ballot(dd < r);
      while (m) {
        int src = __builtin_ctzll(m);
        m &= (m - 1);
        float v = __shfl(dd, src, 64);
        if (v < r) {
          int vi = c0 + src;
          float bdn = __shfl_down(bd, 1, 64);
          int   bin_ = __shfl_down(bi, 1, 64);
          bool c1 = bdn > v;
          bool c2 = bd > v;
          float nb  = c1 ? bdn  : (c2 ? v  : bd);
          int   nbi = c1 ? bin_ : (c2 ? vi : bi);
          bd = (lane < 16) ? nb  : -1e30f;
          bi = (lane < 16) ? nbi : bi;
          r = __shfl(bd, 0, 64);
        }
      }
    }
    if (lane < 16) knn[(size_t)gq * KNN_K + lane] = bi;
  }
}

// -------- K3: grouped linear (gather + GEMM) -------------------------------
// mode 0: stats partials (+ optional hmax/hmin emit for fused path)
// mode 1: final output from precomputed scale/bias (fallback 2nd pass)
__global__ __launch_bounds__(256) void k_gemm(const float* __restrict__ feat,
    const float* __restrict__ xyz, const float* __restrict__ new_xyz,
    const int* __restrict__ knn, const float* __restrict__ W,
    float* __restrict__ part_sum, float* __restrict__ part_sq,
    float* __restrict__ hmax_buf, float* __restrict__ hmin_buf,
    const float* __restrict__ scale, const float* __restrict__ bias,
    float* __restrict__ out, int mode) {
  __shared__ float sg[16][132];
  const int d = threadIdx.x;
  float w[132];
#pragma unroll
  for (int c = 0; c < 132; ++c) {
    if (c < 128)      w[c] = W[(size_t)(3 + c) * COUT + d];
    else if (c < 131) w[c] = W[(size_t)(c - 128) * COUT + d];
    else              w[c] = 0.0f;
  }
  float psum = 0.0f, psq = 0.0f;
  float sc = 0.0f, bb = 0.0f;
  if (mode == 1) { sc = scale[d]; bb = bias[d]; }
#pragma unroll 1
  for (int i = 0; i < GEMM_QPB; ++i) {
    const int gq = blockIdx.x * GEMM_QPB + i;
    const int b = gq >> 11;
    {
      const int row = d >> 4, sub = d & 15;
      const int nidx = knn[(size_t)gq * KNN_K + row];
      const float* frow = feat + ((size_t)b * NPTS + nidx) * CIN;
      const float4 a0 = *(const float4*)(frow + sub * 8);
      const float4 a1 = *(const float4*)(frow + sub * 8 + 4);
      *(float4*)&sg[row][sub * 8]     = a0;
      *(float4*)&sg[row][sub * 8 + 4] = a1;
      if (sub == 0) {
        const float gx = xyz[((size_t)b * NPTS + nidx) * 3 + 0];
        const float gy = xyz[((size_t)b * NPTS + nidx) * 3 + 1];
        const float gz = xyz[((size_t)b * NPTS + nidx) * 3 + 2];
        const float qx = new_xyz[(size_t)gq * 3 + 0];
        const float qy = new_xyz[(size_t)gq * 3 + 1];
        const float qz = new_xyz[(size_t)gq * 3 + 2];
        *(float4*)&sg[row][128] = make_float4(gx - qx, gy - qy, gz - qz, 0.0f);
      }
    }
    __syncthreads();
    float hmax = -1e30f, hmin = 1e30f;
#pragma unroll 1
    for (int k = 0; k < 16; ++k) {
      float a0 = 0.f, a1 = 0.f, a2 = 0.f, a3 = 0.f;
#pragma unroll
      for (int c4 = 0; c4 < 33; ++c4) {
        float4 g = *(const float4*)&sg[k][c4 * 4];
        a0 = fmaf(g.x, w[c4 * 4 + 0], a0);
        a1 = fmaf(g.y, w[c4 * 4 + 1], a1);
        a2 = fmaf(g.z, w[c4 * 4 + 2], a2);
        a3 = fmaf(g.w, w[c4 * 4 + 3], a3);
      }
      float h = (a0 + a1) + (a2 + a3);
      if (mode == 0) { psum += h; psq = fmaf(h, h, psq); }
      hmax = fmaxf(hmax, h); hmin = fminf(hmin, h);
    }
    if (mode == 0) {
      if (hmax_buf) {
        hmax_buf[(size_t)gq * COUT + d] = hmax;
        hmin_buf[(size_t)gq * COUT + d] = hmin;
      }
    } else {
      float hsel = (sc >= 0.0f) ? hmax : hmin;
      float o = fmaxf(fmaf(sc, hsel, bb), 0.0f);
      out[(size_t)gq * COUT + d] = o;
    }
    __syncthreads();
  }
  if (mode == 0) {
    part_sum[(size_t)blockIdx.x * COUT + d] = psum;
    part_sq [(size_t)blockIdx.x * COUT + d] = psq;
  }
}

// ---------------- K4: fold partials into BN scale/bias -----------------------
__global__ __launch_bounds__(256) void k_stats(const float* __restrict__ part_sum,
    const float* __restrict__ part_sq, const float* __restrict__ gamma,
    const float* __restrict__ beta, float* __restrict__ scale,
    float* __restrict__ bias) {
  const int d = threadIdx.x;
  float s = 0.0f, q = 0.0f;
  for (int bl = 0; bl < GEMM_BLOCKS; ++bl) {
    s += part_sum[(size_t)bl * COUT + d];
    q += part_sq[(size_t)bl * COUT + d];
  }
  const float inv = 1.0f / 262144.0f;
  float mean = s * inv;
  float var = q * inv - mean * mean;
  float scv = gamma[d] / sqrtf(var + 1e-5f);
  scale[d] = scv;
  bias[d] = beta[d] - mean * scv;
}

// ---------------- K5: elementwise finalize from hmax/hmin --------------------
__global__ __launch_bounds__(256) void k_final(const float* __restrict__ hmax_buf,
    const float* __restrict__ hmin_buf, const float* __restrict__ scale,
    const float* __restrict__ bias, float* __restrict__ out) {
  const int e4 = (blockIdx.x * 256 + threadIdx.x) * 4;   // 4.19M elements total
  const int d0 = e4 & (COUT - 1);
  const float4 hx = *(const float4*)&hmax_buf[e4];
  const float4 hn = *(const float4*)&hmin_buf[e4];
  const float4 sc = *(const float4*)&scale[d0];
  const float4 bb = *(const float4*)&bias[d0];
  float4 o;
  o.x = fmaxf(fmaf(sc.x, (sc.x >= 0.f) ? hx.x : hn.x, bb.x), 0.f);
  o.y = fmaxf(fmaf(sc.y, (sc.y >= 0.f) ? hx.y : hn.y, bb.y), 0.f);
  o.z = fmaxf(fmaf(sc.z, (sc.z >= 0.f) ? hx.z : hn.z, bb.z), 0.f);
  o.w = fmaxf(fmaf(sc.w, (sc.w >= 0.f) ? hx.w : hn.w, bb.w), 0.f);
  *(float4*)&out[e4] = o;
}

extern "C" void kernel_launch(void* const* d_in, const int* in_sizes, int n_in,
                              void* d_out, int out_size, void* d_ws, size_t ws_size,
                              hipStream_t stream) {
  const float* xyz   = (const float*)d_in[0];
  const float* feat  = (const float*)d_in[1];
  const float* W     = (const float*)d_in[2];
  const float* gamma = (const float*)d_in[3];
  const float* beta  = (const float*)d_in[4];
  float* out_xyz = (float*)d_out;
  float* out_nf  = out_xyz + (size_t)NB * NP * 3;

  // workspace layout
  char* ws = (char*)d_ws;
  int*   knn      = (int*)ws;                                   // 1 MB
  float* hmax_buf = (float*)(ws + (1 << 20));                   // 16.78 MB
  float* hmin_buf = (float*)(ws + (1 << 20) + (GQ_TOTAL * COUT * 4));
  float* part_sum = (float*)(ws + (1 << 20) + 2 * (GQ_TOTAL * COUT * 4));
  float* part_sq  = part_sum + GEMM_BLOCKS * COUT;
  float* scale    = part_sq + GEMM_BLOCKS * COUT;
  float* bias     = scale + COUT;
  const size_t need_fused = (1 << 20) + 2ull * GQ_TOTAL * COUT * 4
                          + 2ull * GEMM_BLOCKS * COUT * 4 + 2 * COUT * 4 + 256;
  const bool fused = ws_size >= need_fused;

  hipLaunchKernelGGL(k_fps, dim3(NB), dim3(512), 0, stream, xyz, out_xyz);
  hipLaunchKernelGGL(k_knn, dim3(256), dim3(256), 0, stream, xyz, out_xyz, knn);
  if (fused) {
    hipLaunchKernelGGL(k_gemm, dim3(GEMM_BLOCKS), dim3(256), 0, stream, feat, xyz,
                       out_xyz, knn, W, part_sum, part_sq, hmax_buf, hmin_buf,
                       (const float*)nullptr, (const float*)nullptr,
                       (float*)nullptr, 0);
    hipLaunchKernelGGL(k_stats, dim3(1), dim3(256), 0, stream, part_sum, part_sq,
                       gamma, beta, scale, bias);
    hipLaunchKernelGGL(k_final, dim3(GQ_TOTAL * COUT / 1024), dim3(256), 0, stream,
                       hmax_buf, hmin_buf, scale, bias, out_nf);
  } else {
    // fallback: two-pass, minimal workspace
    float* f_part_sum = (float*)(ws + (1 << 20));
    float* f_part_sq  = f_part_sum + GEMM_BLOCKS * COUT;
    float* f_scale    = f_part_sq + GEMM_BLOCKS * COUT;
    float* f_bias     = f_scale + COUT;
    hipLaunchKernelGGL(k_gemm, dim3(GEMM_BLOCKS), dim3(256), 0, stream, feat, xyz,
                       out_xyz, knn, W, f_part_sum, f_part_sq,
                       (float*)nullptr, (float*)nullptr,
                       (const float*)nullptr, (const float*)nullptr,
                       (float*)nullptr, 0);
    hipLaunchKernelGGL(k_stats, dim3(1), dim3(256), 0, stream, f_part_sum,
                       f_part_sq, gamma, beta, f_scale, f_bias);
    hipLaunchKernelGGL(k_gemm, dim3(GEMM_BLOCKS), dim3(256), 0, stream, feat, xyz,
                       out_xyz, knn, W, (float*)nullptr, (float*)nullptr,
                       (float*)nullptr, (float*)nullptr, f_scale, f_bias,
                       out_nf, 1);
  }
}